// Round 4
// baseline (4084.432 us; speedup 1.0000x reference)
//
#include <hip/hip_runtime.h>

#define BT 32768
#define CDIM 512
#define KCB 1024
#define NQ 4
#define IDX_BASE (BT*CDIM)
#define LOSS_OFF (BT*CDIM + BT*NQ)
#define TOK 48
#define TPW 12
#define RSTR 513
#define NBLK ((BT + TOK - 1) / TOK)

// mask storage formats: 0=u8, 1=i32, 2=i64, 3=bf16, 4=f32
__device__ __forceinline__ int mask_at(const void* m, int t, int flag) {
  switch (flag) {
    case 0:  return ((const unsigned char*)m)[t] != 0;
    case 1:  return ((const int*)m)[t] != 0;
    case 2:  return ((const unsigned long long*)m)[t] != 0ull;
    case 3:  return ((const unsigned short*)m)[t] != 0;
    default: return ((const float*)m)[t] != 0.0f;
  }
}

// Detect mask storage format, count n_valid, zero the loss accumulator.
__global__ void k_detect(const unsigned char* mask, int* wsi, float* wsf) {
  __shared__ int s_not01, s_off1, s_offn0, s_odd, s_flag, s_count;
  int tid = threadIdx.x;
  if (tid == 0) { s_not01 = 0; s_off1 = 0; s_offn0 = 0; s_odd = 0; s_count = 0; }
  __syncthreads();

  int l_not01 = 0, l_off1 = 0, l_offn0 = 0, l_odd = 0;
  for (int o = tid; o < BT; o += blockDim.x) {
    unsigned char b = mask[o];
    if (b) {
      if (b > 1) l_not01 = 1;
      int m4 = o & 3;
      if (m4 == 1) l_off1 = 1;
      if (m4) l_offn0 = 1;
      if ((o & 7) >= 4) l_odd = 1;
    }
  }
  if (l_not01) atomicOr(&s_not01, 1);
  if (l_off1)  atomicOr(&s_off1, 1);
  if (l_offn0) atomicOr(&s_offn0, 1);
  if (l_odd)   atomicOr(&s_odd, 1);
  __syncthreads();

  if (tid == 0) {
    int fm;
    if (s_not01)      fm = s_off1 ? 3 : 4;   // bf16 : f32
    else if (s_offn0) fm = 0;                // u8
    else if (s_odd)   fm = 1;                // i32
    else              fm = 2;                // i64
    s_flag = fm;
    wsi[0] = fm;
    wsf[3] = 0.0f;                           // loss accumulator
  }
  __syncthreads();

  int fm = s_flag;
  int cnt = 0;
  for (int t = tid; t < BT; t += blockDim.x) cnt += mask_at(mask, t, fm);
  atomicAdd(&s_count, cnt);
  __syncthreads();
  if (tid == 0) wsi[2] = s_count;
}

// b2[row]: XLA-CPU-style SEQUENTIAL sum of rounded products (no fma, no reorder).
__global__ void k_b2(const float* __restrict__ cb, float* __restrict__ b2) {
  int row = blockIdx.x * blockDim.x + threadIdx.x;
  if (row >= NQ * KCB) return;
  const float* p = cb + (size_t)row * CDIM;
  float s = 0.0f;
  for (int c = 0; c < CDIM; ++c) s = __fadd_rn(s, __fmul_rn(p[c], p[c]));
  b2[row] = s;
}

// Main RVQ kernel: bit-replicates XLA-CPU fp32 semantics.
//   a2: sequential scalar sum of rounded squares.
//   ab: sequential-c FMA chain, single accumulator (Eigen sgemm per-element order).
//   dist = fl(fl(a2+b2) - 2*ab); argmin = first occurrence.
//   residual chain: per-element fp32 ops in reference program order.
__global__ __launch_bounds__(256) void k_rvq(const float* __restrict__ x,
                                             const void* __restrict__ mask,
                                             const float* __restrict__ cb,
                                             float* __restrict__ out,
                                             const int* __restrict__ wsi,
                                             const float* __restrict__ b2,
                                             float* __restrict__ accloss) {
  __shared__ float r[TOK][RSTR];
  __shared__ float tile[256][33];
  __shared__ float a2s[TOK];
  __shared__ int   idxs[TOK];
  __shared__ int   vld[TOK];
  __shared__ float lred[4];

  const int tid  = threadIdx.x;
  const int lane = tid & 63;
  const int w    = tid >> 6;
  const int t0   = blockIdx.x * TOK;
  const int wt0  = w * TPW;
  const int fm   = wsi[0];

  if (tid < TOK) {
    int t = t0 + tid;
    vld[tid] = (t < BT) ? mask_at(mask, t, fm) : 0;
  }
  // load residuals (x) for 48 tokens into LDS
  for (int v4 = tid; v4 < TOK * (CDIM / 4); v4 += 256) {
    int tau = v4 >> 7;
    int c4  = v4 & 127;
    int t = t0 + tau;
    float4 f = (t < BT) ? ((const float4*)x)[(size_t)t * (CDIM / 4) + c4]
                        : make_float4(0.f, 0.f, 0.f, 0.f);
    r[tau][c4 * 4 + 0] = f.x; r[tau][c4 * 4 + 1] = f.y;
    r[tau][c4 * 4 + 2] = f.z; r[tau][c4 * 4 + 3] = f.w;
  }
  float lsum = 0.0f;
  __syncthreads();

  for (int i = 0; i < NQ; ++i) {
    // ---- a2: sequential, rounded-product adds ----
    if (tid < TOK) {
      float s = 0.0f;
      for (int c = 0; c < CDIM; ++c) {
        float rv = r[tid][c];
        s = __fadd_rn(s, __fmul_rn(rv, rv));
      }
      a2s[tid] = s;
    }
    __syncthreads();

    float mv[TPW]; int mk[TPW];
#pragma unroll
    for (int tt = 0; tt < TPW; ++tt) { mv[tt] = __builtin_inff(); mk[tt] = 0; }

    for (int k0 = 0; k0 < KCB; k0 += 256) {
      float acc[TPW][4];
#pragma unroll
      for (int tt = 0; tt < TPW; ++tt)
#pragma unroll
        for (int j = 0; j < 4; ++j) acc[tt][j] = 0.0f;

      for (int ct = 0; ct < 16; ++ct) {
        __syncthreads();
        {
          const float4* src = (const float4*)(cb +
              ((size_t)(i * KCB + k0 + tid)) * CDIM + ct * 32);
#pragma unroll
          for (int m = 0; m < 8; ++m) {
            float4 v = src[m];
            tile[tid][m * 4 + 0] = v.x; tile[tid][m * 4 + 1] = v.y;
            tile[tid][m * 4 + 2] = v.z; tile[tid][m * 4 + 3] = v.w;
          }
        }
        __syncthreads();
#pragma unroll 4
        for (int cc = 0; cc < 32; ++cc) {
          int c = ct * 32 + cc;
          float bv0 = tile[lane      ][cc];
          float bv1 = tile[lane + 64 ][cc];
          float bv2 = tile[lane + 128][cc];
          float bv3 = tile[lane + 192][cc];
#pragma unroll
          for (int tt = 0; tt < TPW; ++tt) {
            float rc = r[wt0 + tt][c];
            acc[tt][0] = __fmaf_rn(rc, bv0, acc[tt][0]);
            acc[tt][1] = __fmaf_rn(rc, bv1, acc[tt][1]);
            acc[tt][2] = __fmaf_rn(rc, bv2, acc[tt][2]);
            acc[tt][3] = __fmaf_rn(rc, bv3, acc[tt][3]);
          }
        }
      }
      // fold distances for this k-chunk (k ascending within lane)
      float b20 = b2[i * KCB + k0 + lane];
      float b21 = b2[i * KCB + k0 + lane + 64];
      float b22 = b2[i * KCB + k0 + lane + 128];
      float b23 = b2[i * KCB + k0 + lane + 192];
#pragma unroll
      for (int tt = 0; tt < TPW; ++tt) {
        float a2v = a2s[wt0 + tt];
        float d0 = __fsub_rn(__fadd_rn(a2v, b20), __fmul_rn(2.0f, acc[tt][0]));
        float d1 = __fsub_rn(__fadd_rn(a2v, b21), __fmul_rn(2.0f, acc[tt][1]));
        float d2 = __fsub_rn(__fadd_rn(a2v, b22), __fmul_rn(2.0f, acc[tt][2]));
        float d3 = __fsub_rn(__fadd_rn(a2v, b23), __fmul_rn(2.0f, acc[tt][3]));
        if (d0 < mv[tt]) { mv[tt] = d0; mk[tt] = k0 + lane; }
        if (d1 < mv[tt]) { mv[tt] = d1; mk[tt] = k0 + lane + 64; }
        if (d2 < mv[tt]) { mv[tt] = d2; mk[tt] = k0 + lane + 128; }
        if (d3 < mv[tt]) { mv[tt] = d3; mk[tt] = k0 + lane + 192; }
      }
    }
    // cross-lane argmin, first-occurrence tie-break on k
#pragma unroll
    for (int tt = 0; tt < TPW; ++tt) {
      float v = mv[tt]; int k = mk[tt];
#pragma unroll
      for (int d = 1; d < 64; d <<= 1) {
        float vo = __shfl_xor(v, d, 64);
        int   ko = __shfl_xor(k, d, 64);
        if (vo < v || (vo == v && ko < k)) { v = vo; k = ko; }
      }
      if (lane == 0) idxs[wt0 + tt] = k;
    }
    __syncthreads();

    if (tid < TOK) {
      int t = t0 + tid;
      if (t < BT) out[IDX_BASE + (size_t)t * NQ + i] = vld[tid] ? (float)idxs[tid] : -1.0f;
    }

    // residual update (exact reference op order) + loss
    for (int e = tid; e < TOK * CDIM; e += 256) {
      int tau = e >> 9, c = e & 511;
      int t = t0 + tau;
      if (t >= BT) continue;
      float q  = cb[((size_t)(i * KCB + idxs[tau])) * CDIM + c];
      float rv = r[tau][c];
      float d1 = __fsub_rn(q, rv);
      if (vld[tau]) lsum = __fmaf_rn(d1, d1, lsum);
      float qst = __fadd_rn(rv, d1);
      r[tau][c] = __fsub_rn(rv, qst);
    }
    __syncthreads();
  }

  // x_q = x - r_final (tolerance-safe), 0 for invalid
  for (int e = tid; e < TOK * CDIM; e += 256) {
    int tau = e >> 9, c = e & 511;
    int t = t0 + tau;
    if (t >= BT) continue;
    float xv = x[(size_t)t * CDIM + c];
    out[(size_t)t * CDIM + c] = vld[tau] ? __fsub_rn(xv, r[tau][c]) : 0.0f;
  }

  // loss block-reduce -> one atomic
#pragma unroll
  for (int d = 1; d < 64; d <<= 1) lsum += __shfl_xor(lsum, d, 64);
  if (lane == 0) lred[w] = lsum;
  __syncthreads();
  if (tid == 0) {
    float s = ((lred[0] + lred[1]) + (lred[2] + lred[3]));
    atomicAdd(accloss, s);
  }
}

__global__ void k_loss(const int* wsi, const float* acc, float* out) {
  if (threadIdx.x == 0 && blockIdx.x == 0) {
    float n = (float)wsi[2];
    if (n < 1.0f) n = 1.0f;
    out[LOSS_OFF] = acc[0] * 1.25f / (n * (float)CDIM);
  }
}

extern "C" void kernel_launch(void* const* d_in, const int* in_sizes, int n_in,
                              void* d_out, int out_size, void* d_ws, size_t ws_size,
                              hipStream_t stream) {
  const float* x   = (const float*)d_in[0];
  const void* mask = d_in[1];
  const float* cb  = (const float*)d_in[2];
  int*   wsi = (int*)d_ws;
  float* wsf = (float*)d_ws;
  float* b2  = wsf + 16;   // 4096 floats

  hipLaunchKernelGGL(k_detect, dim3(1), dim3(1024), 0, stream,
                     (const unsigned char*)mask, wsi, wsf);
  hipLaunchKernelGGL(k_b2, dim3(16), dim3(256), 0, stream, cb, b2);
  hipLaunchKernelGGL(k_rvq, dim3(NBLK), dim3(256), 0, stream,
                     x, mask, cb, (float*)d_out, wsi, b2, wsf + 3);
  hipLaunchKernelGGL(k_loss, dim3(1), dim3(1), 0, stream,
                     wsi, wsf + 3, (float*)d_out);
}

// Round 5
// 1374.324 us; speedup vs baseline: 2.9720x; 2.9720x over previous
//
#include <hip/hip_runtime.h>

#define BT 32768
#define CDIM 512
#define KCB 1024
#define NQ 4
#define IDX_BASE (BT*CDIM)
#define LOSS_OFF (BT*CDIM + BT*NQ)

#define TOK 24       // tokens per dot-group
#define TPW 6        // tokens per wave (4 waves/block)
#define KSPLIT 4
#define KRANGE 256   // k per block
#define KCHUNK 128
#define NGRP ((BT + TOK - 1) / TOK)

// ws byte offsets
#define OFF_LIST 256
#define OFF_A2   (OFF_LIST + BT*4)
#define OFF_B2   (OFF_A2 + BT*4)
#define OFF_CV   (OFF_B2 + NQ*KCB*4)
#define OFF_CK   (OFF_CV + KSPLIT*BT*4)

// mask storage formats: 0=u8, 1=i32, 2=i64, 3=bf16, 4=f32
__device__ __forceinline__ int mask_at(const void* m, int t, int flag) {
  switch (flag) {
    case 0:  return ((const unsigned char*)m)[t] != 0;
    case 1:  return ((const int*)m)[t] != 0;
    case 2:  return ((const unsigned long long*)m)[t] != 0ull;
    case 3:  return ((const unsigned short*)m)[t] != 0;
    default: return ((const float*)m)[t] != 0.0f;
  }
}

// Detect mask format, count n_valid, build order-preserving compacted list.
__global__ void k_prep(const unsigned char* mask, int* wsi, float* wsf, int* list) {
  __shared__ int s_not01, s_off1, s_offn0, s_odd, s_fm;
  __shared__ int s_cnt[1024];
  int tid = threadIdx.x;
  if (tid == 0) { s_not01 = 0; s_off1 = 0; s_offn0 = 0; s_odd = 0; }
  __syncthreads();
  int l_not01 = 0, l_off1 = 0, l_offn0 = 0, l_odd = 0;
  for (int o = tid; o < BT; o += 1024) {
    unsigned char b = mask[o];
    if (b) {
      if (b > 1) l_not01 = 1;
      int m4 = o & 3;
      if (m4 == 1) l_off1 = 1;
      if (m4) l_offn0 = 1;
      if ((o & 7) >= 4) l_odd = 1;
    }
  }
  if (l_not01) atomicOr(&s_not01, 1);
  if (l_off1)  atomicOr(&s_off1, 1);
  if (l_offn0) atomicOr(&s_offn0, 1);
  if (l_odd)   atomicOr(&s_odd, 1);
  __syncthreads();
  if (tid == 0) {
    int fm;
    if (s_not01)      fm = s_off1 ? 3 : 4;
    else if (s_offn0) fm = 0;
    else if (s_odd)   fm = 1;
    else              fm = 2;
    s_fm = fm; wsi[0] = fm;
    wsf[8] = 0.0f;                       // loss accumulator
  }
  __syncthreads();
  int fm = s_fm;
  int base = tid * 32, cnt = 0;
  for (int u = 0; u < 32; u++) cnt += mask_at(mask, base + u, fm);
  s_cnt[tid] = cnt;
  __syncthreads();
  if (tid == 0) {
    int run = 0;
    for (int q = 0; q < 1024; q++) { int c = s_cnt[q]; s_cnt[q] = run; run += c; }
    wsi[2] = run;
  }
  __syncthreads();
  int off = s_cnt[tid];
  for (int u = 0; u < 32; u++) {
    int t = base + u;
    if (mask_at(mask, t, fm)) list[off++] = t;
  }
}

// Invalid tokens: x_q row = 0, indices = -1. (Valid rows written later.)
__global__ void k_fill(const void* mask, float* out, const int* wsi) {
  int w = threadIdx.x >> 6, lane = threadIdx.x & 63;
  int t = blockIdx.x * 4 + w;
  if (t >= BT) return;
  if (mask_at(mask, t, wsi[0])) return;
  float4 z = make_float4(0.f, 0.f, 0.f, 0.f);
  float4* p = (float4*)(out + (size_t)t * CDIM) + lane * 2;
  p[0] = z; p[1] = z;
  if (lane < NQ) out[IDX_BASE + (size_t)t * NQ + lane] = -1.0f;
}

// b2: sequential sum of rounded products (XLA-CPU order).
__global__ void k_b2(const float* __restrict__ cb, float* __restrict__ b2) {
  int row = blockIdx.x * blockDim.x + threadIdx.x;
  if (row >= NQ * KCB) return;
  const float* p = cb + (size_t)row * CDIM;
  float s = 0.0f;
  for (int c = 0; c < CDIM; ++c) s = __fadd_rn(s, __fmul_rn(p[c], p[c]));
  b2[row] = s;
}

// r_ws = x for valid tokens; a2 = sequential chain.
__global__ __launch_bounds__(256) void k_init(const float* __restrict__ x,
    float* __restrict__ rws, const int* __restrict__ wsi,
    const int* __restrict__ list, float* __restrict__ a2ws) {
  __shared__ float st[8][CDIM];
  int nv = wsi[2];
  int j0 = blockIdx.x * 8;
  if (j0 >= nv) return;
  int tid = threadIdx.x;
  int j = j0 + (tid >> 5);
  int valid = j < nv;
  int t = list[valid ? j : (nv - 1)];
  int tok = tid >> 5;
  int c0 = (tid & 31) * 16;
  if (valid) {
    const float4* src = (const float4*)(x + (size_t)t * CDIM + c0);
    float4* dst = (float4*)(rws + (size_t)t * CDIM + c0);
#pragma unroll
    for (int q = 0; q < 4; q++) {
      float4 v = src[q]; dst[q] = v;
      *(float4*)&st[tok][c0 + q * 4] = v;
    }
  }
  __syncthreads();
  if (tid < 8) {
    int jj = j0 + tid;
    if (jj < nv) {
      int tt = list[jj];
      float s = 0.f;
      for (int c4 = 0; c4 < 128; c4++) {
        float4 v = *(float4*)&st[tid][c4 * 4];
        s = __fadd_rn(s, __fmul_rn(v.x, v.x));
        s = __fadd_rn(s, __fmul_rn(v.y, v.y));
        s = __fadd_rn(s, __fmul_rn(v.z, v.z));
        s = __fadd_rn(s, __fmul_rn(v.w, v.w));
      }
      a2ws[tt] = s;
    }
  }
}

// Dot kernel: block (g,s) = 24 tokens x 256 k. Exact sequential-c FMA chains.
// r values via scalar (wave-uniform) loads; cb tile in XOR-swizzled LDS.
__global__ __launch_bounds__(256) void k_dot(const float* __restrict__ cb,
    const float* __restrict__ rws, const int* __restrict__ wsi,
    const int* __restrict__ list, const float* __restrict__ a2ws,
    const float* __restrict__ b2ws, float* __restrict__ candv,
    int* __restrict__ candk, int ic) {
  __shared__ float tile[KCHUNK * 32];
  int nv = wsi[2];
  int g = blockIdx.x >> 2, s = blockIdx.x & 3;
  int j0 = g * TOK;
  if (j0 >= nv) return;
  int tid = threadIdx.x;
  int w = __builtin_amdgcn_readfirstlane(tid >> 6);
  int lane = tid & 63;

  const float* rrow[TPW];
  float a2v[TPW];
  int act[TPW], jt_[TPW];
#pragma unroll
  for (int tt = 0; tt < TPW; tt++) {
    int jt = j0 + w * TPW + tt;
    jt_[tt] = jt;
    act[tt] = jt < nv;
    int t = list[act[tt] ? jt : (nv - 1)];
    t = __builtin_amdgcn_readfirstlane(t);
    rrow[tt] = rws + (size_t)t * CDIM;
    a2v[tt] = a2ws[t];
  }
  int lrow = tid >> 1;
  int lhalf = tid & 1;
  const float* cbbase = cb + (size_t)(ic * KCB) * CDIM;

  int rb0 = lane * 32 + ((lane & 7) << 2);
  int rb1 = (lane + 64) * 32 + ((lane & 7) << 2);
  float mv[TPW]; int mk[TPW];
#pragma unroll
  for (int tt = 0; tt < TPW; tt++) { mv[tt] = __builtin_inff(); mk[tt] = 0; }

  int kbase = s * KRANGE;
  for (int kc = 0; kc < 2; kc++) {
    int kb = kbase + kc * KCHUNK;
    float acc[TPW][2];
#pragma unroll
    for (int tt = 0; tt < TPW; tt++) { acc[tt][0] = 0.f; acc[tt][1] = 0.f; }
    for (int ph = 0; ph < 16; ph++) {
      int c0 = ph * 32;
      __syncthreads();
      {
        const float4* src = (const float4*)(cbbase + (size_t)(kb + lrow) * CDIM + c0 + lhalf * 16);
        int r8 = lrow & 7;
#pragma unroll
        for (int q = 0; q < 4; q++) {
          int Wn = lhalf * 4 + q;
          *(float4*)&tile[lrow * 32 + (((Wn ^ r8)) << 2)] = src[q];
        }
      }
      __syncthreads();
#pragma unroll
      for (int w8 = 0; w8 < 8; w8++) {
        float4 cv0 = *(const float4*)&tile[rb0 ^ (w8 << 2)];
        float4 cv1 = *(const float4*)&tile[rb1 ^ (w8 << 2)];
#pragma unroll
        for (int tt = 0; tt < TPW; tt++) {
          const float4 rv = *(const float4*)(rrow[tt] + c0 + (w8 << 2));
          float a0 = acc[tt][0], a1 = acc[tt][1];
          a0 = __fmaf_rn(rv.x, cv0.x, a0); a1 = __fmaf_rn(rv.x, cv1.x, a1);
          a0 = __fmaf_rn(rv.y, cv0.y, a0); a1 = __fmaf_rn(rv.y, cv1.y, a1);
          a0 = __fmaf_rn(rv.z, cv0.z, a0); a1 = __fmaf_rn(rv.z, cv1.z, a1);
          a0 = __fmaf_rn(rv.w, cv0.w, a0); a1 = __fmaf_rn(rv.w, cv1.w, a1);
          acc[tt][0] = a0; acc[tt][1] = a1;
        }
      }
    }
    float b20 = b2ws[ic * KCB + kb + lane];
    float b21 = b2ws[ic * KCB + kb + lane + 64];
#pragma unroll
    for (int tt = 0; tt < TPW; tt++) {
      float d0 = __fsub_rn(__fadd_rn(a2v[tt], b20), __fmul_rn(2.0f, acc[tt][0]));
      float d1 = __fsub_rn(__fadd_rn(a2v[tt], b21), __fmul_rn(2.0f, acc[tt][1]));
      if (d0 < mv[tt]) { mv[tt] = d0; mk[tt] = kb + lane; }
      if (d1 < mv[tt]) { mv[tt] = d1; mk[tt] = kb + lane + 64; }
    }
  }
#pragma unroll
  for (int tt = 0; tt < TPW; tt++) {
    float v = mv[tt]; int k = mk[tt];
#pragma unroll
    for (int d = 1; d < 64; d <<= 1) {
      float vo = __shfl_xor(v, d, 64);
      int   ko = __shfl_xor(k, d, 64);
      if (vo < v || (vo == v && ko < k)) { v = vo; k = ko; }
    }
    if (lane == 0 && act[tt]) {
      candv[s * BT + jt_[tt]] = v;
      candk[s * BT + jt_[tt]] = k;
    }
  }
}

// Combine candidates, write idx, exact residual update (+loss, +a2 or x_q).
__global__ __launch_bounds__(256) void k_upd(const float* __restrict__ x,
    const float* __restrict__ cb, float* __restrict__ rws,
    const int* __restrict__ wsi, const int* __restrict__ list,
    float* __restrict__ a2ws, const float* __restrict__ candv,
    const int* __restrict__ candk, float* __restrict__ out,
    float* __restrict__ lossacc, int ic) {
  __shared__ float st[8][CDIM];
  __shared__ int s_k[8];
  __shared__ float s_l[4];
  int nv = wsi[2];
  int j0 = blockIdx.x * 8;
  if (j0 >= nv) return;
  int tid = threadIdx.x;
  if (tid < 8) {
    int jj = j0 + tid;
    int kw = 0;
    if (jj < nv) {
      float bv = __builtin_inff(); int bk = 0;
      for (int s = 0; s < KSPLIT; s++) {
        float v = candv[s * BT + jj]; int k = candk[s * BT + jj];
        if (v < bv || (v == bv && k < bk)) { bv = v; bk = k; }
      }
      kw = bk;
      int t = list[jj];
      out[IDX_BASE + (size_t)t * NQ + ic] = (float)kw;
    }
    s_k[tid] = kw;
  }
  __syncthreads();
  int j = j0 + (tid >> 5);
  int valid = j < nv;
  int t = list[valid ? j : (nv - 1)];
  int tok = tid >> 5;
  int c0 = (tid & 31) * 16;
  int kw = s_k[tok];
  float lsum = 0.f;
  if (valid) {
    const float4* qp = (const float4*)(cb + (size_t)(ic * KCB + kw) * CDIM + c0);
    float4* rp = (float4*)(rws + (size_t)t * CDIM + c0);
    const float4* xp = (const float4*)(x + (size_t)t * CDIM + c0);
#pragma unroll
    for (int q = 0; q < 4; q++) {
      float4 qv = qp[q], rv = rp[q];
      float4 d, rn;
      d.x = __fsub_rn(qv.x, rv.x); d.y = __fsub_rn(qv.y, rv.y);
      d.z = __fsub_rn(qv.z, rv.z); d.w = __fsub_rn(qv.w, rv.w);
      rn.x = __fsub_rn(rv.x, __fadd_rn(rv.x, d.x));
      rn.y = __fsub_rn(rv.y, __fadd_rn(rv.y, d.y));
      rn.z = __fsub_rn(rv.z, __fadd_rn(rv.z, d.z));
      rn.w = __fsub_rn(rv.w, __fadd_rn(rv.w, d.w));
      lsum = __fmaf_rn(d.x, d.x, lsum); lsum = __fmaf_rn(d.y, d.y, lsum);
      lsum = __fmaf_rn(d.z, d.z, lsum); lsum = __fmaf_rn(d.w, d.w, lsum);
      if (ic < 3) {
        rp[q] = rn;
        *(float4*)&st[tok][c0 + q * 4] = rn;
      } else {
        float4 xv = xp[q], xq;
        xq.x = __fsub_rn(xv.x, rn.x); xq.y = __fsub_rn(xv.y, rn.y);
        xq.z = __fsub_rn(xv.z, rn.z); xq.w = __fsub_rn(xv.w, rn.w);
        rp[q] = xq;
      }
    }
  }
  if (ic < 3) {
    __syncthreads();
    if (tid < 8) {
      int jj = j0 + tid;
      if (jj < nv) {
        int t2 = list[jj];
        float ss = 0.f;
        for (int c4 = 0; c4 < 128; c4++) {
          float4 v = *(float4*)&st[tid][c4 * 4];
          ss = __fadd_rn(ss, __fmul_rn(v.x, v.x));
          ss = __fadd_rn(ss, __fmul_rn(v.y, v.y));
          ss = __fadd_rn(ss, __fmul_rn(v.z, v.z));
          ss = __fadd_rn(ss, __fmul_rn(v.w, v.w));
        }
        a2ws[t2] = ss;
      }
    }
  }
#pragma unroll
  for (int d = 1; d < 64; d <<= 1) lsum += __shfl_xor(lsum, d, 64);
  if ((tid & 63) == 0) s_l[tid >> 6] = lsum;
  __syncthreads();
  if (tid == 0) atomicAdd(lossacc, (s_l[0] + s_l[1]) + (s_l[2] + s_l[3]));
}

__global__ void k_loss(const int* wsi, const float* acc, float* out) {
  if (threadIdx.x == 0 && blockIdx.x == 0) {
    float n = (float)wsi[2];
    if (n < 1.0f) n = 1.0f;
    out[LOSS_OFF] = acc[0] * 1.25f / (n * (float)CDIM);
  }
}

extern "C" void kernel_launch(void* const* d_in, const int* in_sizes, int n_in,
                              void* d_out, int out_size, void* d_ws, size_t ws_size,
                              hipStream_t stream) {
  const float* x   = (const float*)d_in[0];
  const void* mask = d_in[1];
  const float* cb  = (const float*)d_in[2];
  float* out = (float*)d_out;
  char* ws = (char*)d_ws;
  int*   wsi  = (int*)ws;
  float* wsf  = (float*)ws;
  int*   list = (int*)(ws + OFF_LIST);
  float* a2w  = (float*)(ws + OFF_A2);
  float* b2w  = (float*)(ws + OFF_B2);
  float* cv   = (float*)(ws + OFF_CV);
  int*   ck   = (int*)(ws + OFF_CK);
  float* rws  = out;   // x_q region doubles as residual workspace (token layout)

  hipLaunchKernelGGL(k_prep, dim3(1), dim3(1024), 0, stream,
                     (const unsigned char*)mask, wsi, wsf, list);
  hipLaunchKernelGGL(k_fill, dim3(BT / 4), dim3(256), 0, stream, mask, out, wsi);
  hipLaunchKernelGGL(k_b2, dim3(16), dim3(256), 0, stream, cb, b2w);
  hipLaunchKernelGGL(k_init, dim3(BT / 8), dim3(256), 0, stream, x, rws, wsi, list, a2w);
  for (int ic = 0; ic < NQ; ic++) {
    hipLaunchKernelGGL(k_dot, dim3(NGRP * KSPLIT), dim3(256), 0, stream,
                       cb, rws, wsi, list, a2w, b2w, cv, ck, ic);
    hipLaunchKernelGGL(k_upd, dim3(BT / 8), dim3(256), 0, stream,
                       x, cb, rws, wsi, list, a2w, cv, ck, out, wsf + 8, ic);
  }
  hipLaunchKernelGGL(k_loss, dim3(1), dim3(1), 0, stream, wsi, wsf + 8, out);
}